// Round 3
// baseline (295.534 us; speedup 1.0000x reference)
//
#include <hip/hip_runtime.h>

// ---------------------------------------------------------------------------
// GCN variational encoder (mu, logvar) on MI355X — round 3.
//   h[n] = dinv[n] * ( dinv[n]*x[n] + sum_{s->n} dinv[s]*x[s] )
//   mu = h@Wmu + bmu ; logvar = h@Wlv + blv
// CSR via counting sort (no float atomics), register-gather aggregation,
// fused dual GEMM.
// R3 changes: GEMM processes 4 rows/thread concurrently (8 indep FMA chains,
// was latency-bound at 28% VALUBusy); agg gathers 4 edges per wave-instr
// (16 lanes x float4 = one 256B row each) + shfl-xor reduce.
// ---------------------------------------------------------------------------

__global__ void k_zero(int* __restrict__ p, int n) {
    int i = blockIdx.x * blockDim.x + threadIdx.x;
    if (i < n) p[i] = 0;
}

__global__ void k_deg(const int* __restrict__ dst, int e, int* __restrict__ deg) {
    int i = blockIdx.x * blockDim.x + threadIdx.x;
    if (i < e) atomicAdd(&deg[dst[i]], 1);
}

__global__ void k_dinv(const int* __restrict__ deg, float* __restrict__ dinv, int n) {
    int i = blockIdx.x * blockDim.x + threadIdx.x;
    if (i < n) dinv[i] = rsqrtf((float)(deg[i] + 1));  // +1 = self loop
}

// --- 3-kernel exclusive scan of deg[] -> start[] ---------------------------
__global__ void k_scan_block(const int* __restrict__ deg, int* __restrict__ start,
                             int* __restrict__ partial, int n) {
    __shared__ int sm[256];
    const int tid = threadIdx.x;
    const int i = blockIdx.x * 256 + tid;
    int v = (i < n) ? deg[i] : 0;
    sm[tid] = v;
    __syncthreads();
    for (int off = 1; off < 256; off <<= 1) {
        int t = (tid >= off) ? sm[tid - off] : 0;
        __syncthreads();
        sm[tid] += t;
        __syncthreads();
    }
    if (i < n) start[i] = sm[tid] - v;
    if (tid == 255) partial[blockIdx.x] = sm[255];
}

__global__ void k_scan_partial(int* __restrict__ partial, int nb) {
    __shared__ int sm[512];
    const int tid = threadIdx.x;
    int v = (tid < nb) ? partial[tid] : 0;
    sm[tid] = v;
    __syncthreads();
    for (int off = 1; off < 512; off <<= 1) {
        int t = (tid >= off) ? sm[tid - off] : 0;
        __syncthreads();
        sm[tid] += t;
        __syncthreads();
    }
    if (tid < nb) partial[tid] = sm[tid] - v;
}

__global__ void k_scan_add(int* __restrict__ start, int* __restrict__ cursor,
                           const int* __restrict__ partial, int n) {
    int i = blockIdx.x * blockDim.x + threadIdx.x;
    if (i < n) {
        int s = start[i] + partial[i >> 8];
        start[i] = s;
        cursor[i] = s;
    }
}

__global__ void k_sort(const int* __restrict__ src, const int* __restrict__ dst, int e,
                       int* __restrict__ cursor, int* __restrict__ srcSorted) {
    int i = blockIdx.x * blockDim.x + threadIdx.x;
    if (i < e) {
        int d = dst[i];
        int p = atomicAdd(&cursor[d], 1);
        srcSorted[p] = src[i];
    }
}

// --- gather aggregation: one wave per node, 4 edges per iteration ----------
// lane = sub*16 + c4: 16-lane group `sub` handles edge k+sub, loading the
// full 256B source row as float4 (1KB per wave gather instr). Partial sums
// reduced across sub-groups with 2 shfl_xor rounds.
__global__ __launch_bounds__(256) void k_agg(
        const float* __restrict__ x, const float* __restrict__ dinv,
        const int* __restrict__ start, const int* __restrict__ deg,
        const int* __restrict__ srcSorted, float* __restrict__ h, int n) {
    const int lane = threadIdx.x & 63;
    const int node = blockIdx.x * 4 + (threadIdx.x >> 6);
    if (node >= n) return;
    const int sub = lane >> 4;    // 0..3: edge slot
    const int c4  = lane & 15;    // float4 column
    const float dn = dinv[node];
    const int s0 = start[node];
    const int d  = deg[node];
    const float4* __restrict__ x4 = (const float4*)x;

    float4 acc = make_float4(0.f, 0.f, 0.f, 0.f);
    for (int k = sub; k < d; k += 4) {
        int s = srcSorted[s0 + k];               // uniform within 16-lane group
        float w = dinv[s];
        float4 v = x4[(size_t)s * 16 + c4];      // 256B row gather
        acc.x = fmaf(w, v.x, acc.x);
        acc.y = fmaf(w, v.y, acc.y);
        acc.z = fmaf(w, v.z, acc.z);
        acc.w = fmaf(w, v.w, acc.w);
    }
    // reduce partial sums across the 4 sub-groups (lanes ^16, ^32)
    acc.x += __shfl_xor(acc.x, 16); acc.x += __shfl_xor(acc.x, 32);
    acc.y += __shfl_xor(acc.y, 16); acc.y += __shfl_xor(acc.y, 32);
    acc.z += __shfl_xor(acc.z, 16); acc.z += __shfl_xor(acc.z, 32);
    acc.w += __shfl_xor(acc.w, 16); acc.w += __shfl_xor(acc.w, 32);

    if (sub == 0) {
        float4 v = x4[(size_t)node * 16 + c4];   // self loop
        float4 o;
        o.x = dn * fmaf(dn, v.x, acc.x);
        o.y = dn * fmaf(dn, v.y, acc.y);
        o.z = dn * fmaf(dn, v.z, acc.z);
        o.w = dn * fmaf(dn, v.w, acc.w);
        ((float4*)h)[(size_t)node * 16 + c4] = o;
    }
}

// --- fused dual GEMM: mu = h@Wmu+bmu, lv = h@Wlv+blv ------------------------
// 4 rows in flight per thread -> 8 independent FMA chains (was 2, latency-
// bound at 28% VALUBusy). W columns in registers, h tile in LDS (broadcast
// reads). In-place safe: each block stages its own 64 h-rows before writing.
__global__ __launch_bounds__(256) void k_gemm2(
        const float* __restrict__ h,
        const float* __restrict__ Wmu, const float* __restrict__ bmu,
        const float* __restrict__ Wlv, const float* __restrict__ blv,
        float* __restrict__ mu, float* __restrict__ lv, int n) {
    __shared__ float4 h4[64 * 16];
    const int tid = threadIdx.x;
    const int row0 = blockIdx.x * 64;

    for (int t = tid; t < 1024; t += 256) {
        int r = t >> 4, c = t & 15;
        int row = row0 + r;
        h4[t] = (row < n) ? ((const float4*)h)[(size_t)row * 16 + c]
                          : make_float4(0.f, 0.f, 0.f, 0.f);
    }

    const int j = tid & 63;
    const int rg = tid >> 6;
    float wmu_r[64], wlv_r[64];
    #pragma unroll
    for (int k = 0; k < 64; ++k) {
        wmu_r[k] = Wmu[k * 64 + j];
        wlv_r[k] = Wlv[k * 64 + j];
    }
    const float bm = bmu[j];
    const float bl = blv[j];
    __syncthreads();

    #pragma unroll
    for (int ib = 0; ib < 4; ++ib) {
        const int r0 = rg * 16 + ib * 4;
        float am0 = bm, am1 = bm, am2 = bm, am3 = bm;
        float al0 = bl, al1 = bl, al2 = bl, al3 = bl;
        #pragma unroll
        for (int kq = 0; kq < 16; ++kq) {
            float4 h0 = h4[(r0 + 0) * 16 + kq];
            float4 h1 = h4[(r0 + 1) * 16 + kq];
            float4 h2 = h4[(r0 + 2) * 16 + kq];
            float4 h3 = h4[(r0 + 3) * 16 + kq];
            float wm0 = wmu_r[4 * kq], wm1 = wmu_r[4 * kq + 1];
            float wm2 = wmu_r[4 * kq + 2], wm3 = wmu_r[4 * kq + 3];
            float wl0 = wlv_r[4 * kq], wl1 = wlv_r[4 * kq + 1];
            float wl2 = wlv_r[4 * kq + 2], wl3 = wlv_r[4 * kq + 3];
            am0 = fmaf(h0.x, wm0, am0); am0 = fmaf(h0.y, wm1, am0);
            am0 = fmaf(h0.z, wm2, am0); am0 = fmaf(h0.w, wm3, am0);
            am1 = fmaf(h1.x, wm0, am1); am1 = fmaf(h1.y, wm1, am1);
            am1 = fmaf(h1.z, wm2, am1); am1 = fmaf(h1.w, wm3, am1);
            am2 = fmaf(h2.x, wm0, am2); am2 = fmaf(h2.y, wm1, am2);
            am2 = fmaf(h2.z, wm2, am2); am2 = fmaf(h2.w, wm3, am2);
            am3 = fmaf(h3.x, wm0, am3); am3 = fmaf(h3.y, wm1, am3);
            am3 = fmaf(h3.z, wm2, am3); am3 = fmaf(h3.w, wm3, am3);
            al0 = fmaf(h0.x, wl0, al0); al0 = fmaf(h0.y, wl1, al0);
            al0 = fmaf(h0.z, wl2, al0); al0 = fmaf(h0.w, wl3, al0);
            al1 = fmaf(h1.x, wl0, al1); al1 = fmaf(h1.y, wl1, al1);
            al1 = fmaf(h1.z, wl2, al1); al1 = fmaf(h1.w, wl3, al1);
            al2 = fmaf(h2.x, wl0, al2); al2 = fmaf(h2.y, wl1, al2);
            al2 = fmaf(h2.z, wl2, al2); al2 = fmaf(h2.w, wl3, al2);
            al3 = fmaf(h3.x, wl0, al3); al3 = fmaf(h3.y, wl1, al3);
            al3 = fmaf(h3.z, wl2, al3); al3 = fmaf(h3.w, wl3, al3);
        }
        int row = row0 + r0;
        if (row + 0 < n) { mu[(size_t)(row + 0) * 64 + j] = am0; lv[(size_t)(row + 0) * 64 + j] = al0; }
        if (row + 1 < n) { mu[(size_t)(row + 1) * 64 + j] = am1; lv[(size_t)(row + 1) * 64 + j] = al1; }
        if (row + 2 < n) { mu[(size_t)(row + 2) * 64 + j] = am2; lv[(size_t)(row + 2) * 64 + j] = al2; }
        if (row + 3 < n) { mu[(size_t)(row + 3) * 64 + j] = am3; lv[(size_t)(row + 3) * 64 + j] = al3; }
    }
}

extern "C" void kernel_launch(void* const* d_in, const int* in_sizes, int n_in,
                              void* d_out, int out_size, void* d_ws, size_t ws_size,
                              hipStream_t stream) {
    const float* x   = (const float*)d_in[0];
    const int* eidx  = (const int*)d_in[1];
    const float* Wmu = (const float*)d_in[2];
    const float* bmu = (const float*)d_in[3];
    const float* Wlv = (const float*)d_in[4];
    const float* blv = (const float*)d_in[5];

    const int N = in_sizes[0] / 64;
    const int E = in_sizes[1] / 2;
    const int* src = eidx;
    const int* dst = eidx + E;

    char* ws = (char*)d_ws;
    size_t off = 0;
    int*   deg    = (int*)(ws + off);   off += ((size_t)N * 4 + 255) & ~(size_t)255;
    float* dinv   = (float*)(ws + off); off += ((size_t)N * 4 + 255) & ~(size_t)255;
    int*   start  = (int*)(ws + off);   off += ((size_t)N * 4 + 255) & ~(size_t)255;
    int*   cursor = (int*)(ws + off);   off += ((size_t)N * 4 + 255) & ~(size_t)255;
    int*   partial= (int*)(ws + off);   off += 512 * 4;
    int*   srcS   = (int*)(ws + off);   off += ((size_t)E * 4 + 255) & ~(size_t)255;

    float* mu = (float*)d_out;             // h aliases mu (in-place GEMM)
    float* lv = mu + (size_t)N * 64;
    float* h  = mu;

    const int B = 256;
    const int nb = (N + 255) / 256;        // 391 <= 512

    k_zero<<<(N + B - 1) / B, B, 0, stream>>>(deg, N);
    k_deg<<<(E + B - 1) / B, B, 0, stream>>>(dst, E, deg);
    k_dinv<<<(N + B - 1) / B, B, 0, stream>>>(deg, dinv, N);

    k_scan_block<<<nb, 256, 0, stream>>>(deg, start, partial, N);
    k_scan_partial<<<1, 512, 0, stream>>>(partial, nb);
    k_scan_add<<<(N + B - 1) / B, B, 0, stream>>>(start, cursor, partial, N);

    k_sort<<<(E + B - 1) / B, B, 0, stream>>>(src, dst, E, cursor, srcS);

    k_agg<<<(N + 3) / 4, 256, 0, stream>>>(x, dinv, start, deg, srcS, h, N);

    k_gemm2<<<(N + 63) / 64, 256, 0, stream>>>(h, Wmu, bmu, Wlv, blv, mu, lv, N);
}